// Round 2
// baseline (364.391 us; speedup 1.0000x reference)
//
#include <hip/hip_runtime.h>
#include <hip/hip_cooperative_groups.h>

namespace cg = cooperative_groups;

typedef float  f32x4   __attribute__((ext_vector_type(4)));
typedef float  f32x16  __attribute__((ext_vector_type(16)));
typedef short  bf16x8  __attribute__((ext_vector_type(8)));
typedef unsigned short u16;

constexpr int B_ = 4;
constexpr int C_ = 128;
constexpr int N_ = 4096;
constexpr int G_ = 8;
constexpr int CperG = 16;
constexpr float EPS_ = 1e-5f;
// 1/sqrt(C) * log2(e): Q pre-scaled so the softmax exp is a bare v_exp_f32 (exp2)
constexpr float SCALE2_ = 0.08838834764831845f * 1.4426950408889634f;

__device__ inline u16 f2bf(float f) {
    union { float f; unsigned u; } v; v.f = f;
    unsigned r = v.u + 0x7fffu + ((v.u >> 16) & 1u);  // RNE
    return (u16)(r >> 16);
}
// hardware packed f32->bf16 (RNE), 1 instr instead of ~10
__device__ inline unsigned cvtpk(float lo, float hi) {
    unsigned r;
    asm("v_cvt_pk_bf16_f32 %0, %1, %2" : "=v"(r) : "v"(lo), "v"(hi));
    return r;
}

constexpr int HS = 136;   // padded row stride (u16)

// ---------------- shared-memory union across phases ----------------
struct SMb { u16 hs[64*HS]; u16 Wl2[2][64*HS]; float gm[8], gr[8]; };
struct SMc { float Ob[64*132]; float lW[8][32]; };
union  SMu { struct { float rs[8], rss[8]; } a; SMb b; SMc c; };

// =======================================================================
// FUSED cooperative kernel: Phase A (GN partials + weight->bf16),
// grid.sync, Phase B (QKV via MFMA -> Qt/Ksw/Vsw + norms), grid.sync,
// Phase C (streaming MFMA attention + proj + residual; identical to R1).
// grid = 256 blocks x 512 threads: exactly 1 block/CU (co-resident).
// =======================================================================
__global__ __launch_bounds__(512, 2) void fused_kernel(
    const float* __restrict__ x,  const float* __restrict__ nw, const float* __restrict__ nb,
    const float* __restrict__ qw, const float* __restrict__ qb,
    const float* __restrict__ pw, const float* __restrict__ pb,
    float* __restrict__ out,
    float* __restrict__ stats2, float* __restrict__ qn2, int* __restrict__ kmaxI,
    u16* __restrict__ qwbf, u16* __restrict__ pwbf,
    u16* __restrict__ Qt,  u16* __restrict__ Ksw, u16* __restrict__ Vsw)
{
    __shared__ SMu sm;
    cg::grid_group grid = cg::this_grid();
    int blk = blockIdx.x, t = threadIdx.x;

    // ---------------- Phase A: GN partial sums + weight conversion ----------------
    {
        int bg = blk >> 3, chunk = blk & 7;
        const float4* xp = (const float4*)(x + (size_t)bg * (CperG * N_)) + chunk * 2048;
        float s = 0.f, ss = 0.f;
        #pragma unroll
        for (int i = 0; i < 4; ++i) {
            float4 v = xp[t + (i << 9)];
            s  += v.x + v.y + v.z + v.w;
            ss += v.x*v.x + v.y*v.y + v.z*v.z + v.w*v.w;
        }
        #pragma unroll
        for (int off = 32; off > 0; off >>= 1) {
            s  += __shfl_down(s, off);
            ss += __shfl_down(ss, off);
        }
        int wv = t >> 6, ln = t & 63;
        if (ln == 0) { sm.a.rs[wv] = s; sm.a.rss[wv] = ss; }
        if (t < 64) {  // 256 blocks x 64 float4 = all 64K weight floats
            int fidx = (blk * 64 + t) * 4;
            float4 v; u16* dst;
            if (fidx < 3*C_*C_) { v = *(const float4*)(qw + fidx); dst = qwbf + fidx; }
            else { int j2 = fidx - 3*C_*C_; v = *(const float4*)(pw + j2); dst = pwbf + j2; }
            ushort4 o;
            o.x = f2bf(v.x); o.y = f2bf(v.y); o.z = f2bf(v.z); o.w = f2bf(v.w);
            *(ushort4*)dst = o;
        }
        if (blk == 0 && t >= 128 && t < 132) kmaxI[t - 128] = (int)0x80000000;  // INT_MIN
        __syncthreads();
        if (t == 0) {
            float S = 0.f, SS = 0.f;
            #pragma unroll
            for (int k2 = 0; k2 < 8; ++k2) { S += sm.a.rs[k2]; SS += sm.a.rss[k2]; }
            stats2[blk*2]     = S;
            stats2[blk*2 + 1] = SS;
        }
    }
    __threadfence();
    grid.sync();

    // ---------------- Phase B: QKV. 8 waves: grp0 = ck 0-2 (Q + K-lo),
    // grp1 = ck 3-5 (K-hi + V). One LDS exchange combines the split nk. ----------------
    {
        int n0 = (blk & 63) * 64;
        int b  = blk >> 6;
        const float invM = 1.f / (float)(CperG * N_);
        if (t < 8) {
            const float* sp = stats2 + (size_t)(b*G_ + t)*16;
            float S = 0.f, SS = 0.f;
            #pragma unroll
            for (int k2 = 0; k2 < 8; ++k2) { S += sp[k2*2]; SS += sp[k2*2 + 1]; }
            float mean = S * invM;
            sm.b.gm[t] = mean;
            sm.b.gr[t] = rsqrtf(SS * invM - mean*mean + EPS_);
        }
        __syncthreads();
        #pragma unroll
        for (int r = 0; r < 4; ++r) {
            int idx = t + (r << 9);
            int c = idx >> 4, n4 = idx & 15;
            int g = c >> 4;
            float wgt = nw[c] * sm.b.gr[g];
            float bia = nb[c] - sm.b.gm[g] * wgt;
            float4 xv = *(const float4*)(x + ((size_t)(b*C_ + c))*N_ + n0 + n4*4);
            int base = (n4*4) * HS + c;
            unsigned u01 = cvtpk(xv.x*wgt + bia, xv.y*wgt + bia);
            unsigned u23 = cvtpk(xv.z*wgt + bia, xv.w*wgt + bia);
            sm.b.hs[base         ] = (u16)(u01 & 0xffffu);
            sm.b.hs[base +     HS] = (u16)(u01 >> 16);
            sm.b.hs[base + 2 * HS] = (u16)(u23 & 0xffffu);
            sm.b.hs[base + 3 * HS] = (u16)(u23 >> 16);
        }
        __syncthreads();
        int w = t >> 6, lane = t & 63, lo = lane & 15, hi = lane >> 4;
        int wl = w & 3, grp = w >> 2;
        bf16x8 hf[4];
        #pragma unroll
        for (int ch = 0; ch < 4; ++ch)
            hf[ch] = *(const bf16x8*)(sm.b.hs + (16*wl + lo)*HS + 32*ch + 8*hi);
        int Tb = (n0 >> 5) + (wl >> 1);
        u16* Wl = sm.b.Wl2[grp];
        float nq = 0.f, nk = 0.f;
        for (int j = 0; j < 3; ++j) {
            int ck = 3*grp + j;
            {
                int tl = t & 255;          // each 256-thread group stages its own Wl
                int r = tl >> 2, p = tl & 3;
                const u16* src = qwbf + (size_t)(ck*64 + r)*C_ + p*32;
                u16* dst = Wl + r*HS + p*32;
                #pragma unroll
                for (int k2 = 0; k2 < 4; ++k2)
                    *(uint4*)(dst + 8*k2) = *(const uint4*)(src + 8*k2);
            }
            __syncthreads();
            #pragma unroll
            for (int ot = 0; ot < 4; ++ot) {
                int o16 = ck*64 + ot*16;
                bf16x8 wf[4];
                #pragma unroll
                for (int ch = 0; ch < 4; ++ch)
                    wf[ch] = *(const bf16x8*)(Wl + (ot*16 + lo)*HS + 32*ch + 8*hi);
                if (o16 < 2*C_) {
                    // Q/K: A=W (m=o), B=h (n=px) -> lane holds D[o=o16+4hi+r][px=n0+16wl+lo]
                    f32x4 acc = (f32x4){0.f, 0.f, 0.f, 0.f};
                    #pragma unroll
                    for (int ch = 0; ch < 4; ++ch)
                        acc = __builtin_amdgcn_mfma_f32_16x16x32_bf16(wf[ch], hf[ch], acc, 0, 0, 0);
                    float4 bv = *(const float4*)(qb + o16 + 4*hi);
                    int n = n0 + 16*wl + lo;
                    if (o16 < C_) {
                        float q0 = (acc[0] + bv.x) * SCALE2_;
                        float q1 = (acc[1] + bv.y) * SCALE2_;
                        float q2 = (acc[2] + bv.z) * SCALE2_;
                        float q3 = (acc[3] + bv.w) * SCALE2_;
                        nq += (q0*q0 + q1*q1) + (q2*q2 + q3*q3);
                        union { ushort4 s4; unsigned u[2]; } o4;
                        o4.u[0] = cvtpk(q0, q1);
                        o4.u[1] = cvtpk(q2, q3);
                        *(ushort4*)(Qt + ((size_t)b*N_ + n)*C_ + o16 + 4*hi) = o4.s4;
                    } else {
                        float k0 = acc[0] + bv.x, k1 = acc[1] + bv.y;
                        float k2 = acc[2] + bv.z, k3 = acc[3] + bv.w;
                        nk += (k0*k0 + k1*k1) + (k2*k2 + k3*k3);
                        union { ushort4 s4; unsigned u[2]; } o4;
                        o4.u[0] = cvtpk(k0, k1);
                        o4.u[1] = cvtpk(k2, k3);
                        int cc = (o16 - C_) >> 4;
                        int lp = (16*(wl & 1) + lo) + 32*(hi >> 1);
                        size_t fb = ((size_t)(b*128 + Tb)*8 + cc)*512;
                        *(ushort4*)(Ksw + fb + lp*8 + 4*(hi & 1)) = o4.s4;
                    }
                } else {
                    // V: A=h (m=px), B=W (n=o) -> lane holds D[px=n0+16wl+4hi+r][o=o16-256+lo]
                    f32x4 acc = (f32x4){0.f, 0.f, 0.f, 0.f};
                    #pragma unroll
                    for (int ch = 0; ch < 4; ++ch)
                        acc = __builtin_amdgcn_mfma_f32_16x16x32_bf16(hf[ch], wf[ch], acc, 0, 0, 0);
                    float bia = qb[o16 + lo];
                    union { ushort4 s4; unsigned u[2]; } o4;
                    o4.u[0] = cvtpk(acc[0] + bia, acc[1] + bia);
                    o4.u[1] = cvtpk(acc[2] + bia, acc[3] + bia);
                    int m  = (o16 - 2*C_) >> 4;
                    int ct = m >> 1;
                    int lp = (16*(m & 1) + lo) + 32*(hi & 1);
                    size_t fb = (((size_t)(b*4 + ct)*128 + Tb)*2 + (wl & 1))*512;
                    *(ushort4*)(Vsw + fb + lp*8 + 4*(hi >> 1)) = o4.s4;
                }
            }
            __syncthreads();
        }
        if (grp == 0) {
            nq += __shfl_xor(nq, 16); nq += __shfl_xor(nq, 32);
            if (lane < 16) qn2[(size_t)b*N_ + n0 + 16*wl + lo] = nq;
        }
        // combine split ||k||^2: grp1 (chans 64-127) -> LDS -> grp0 adds its 0-63
        float* nkx = (float*)sm.b.hs;   // hs dead after j-loop (barrier above)
        nk += __shfl_xor(nk, 16); nk += __shfl_xor(nk, 32);
        if (grp == 1 && lane < 16) nkx[wl*16 + lo] = nk;
        __syncthreads();
        if (grp == 0) {
            nk += nkx[wl*16 + lo];
            #pragma unroll
            for (int off = 1; off < 16; off <<= 1)
                nk = fmaxf(nk, __shfl_xor(nk, off));
            if (lane == 0) atomicMax(&kmaxI[b], __float_as_int(nk));
        }
    }
    __threadfence();
    grid.sync();

    // ---------------- Phase C: streaming MFMA attention (identical to R1) ----------------
    {
        int lb = blk;
        int b  = lb & 3;                       // XCD-swizzle: batch locality in L2
        int i0 = 64 * (lb >> 2);
        int w = t >> 6, lane = t & 63;
        int l31 = lane & 31, h = lane >> 5;
        int qt = w >> 2, ks = w & 3;

        float kmax = sqrtf(__int_as_float(kmaxI[b]));
        float mq = sqrtf(qn2[(size_t)b*N_ + i0 + 32*qt + l31]) * kmax * 1.02f + 1e-6f;

        const u16* Qb = Qt + (size_t)b*N_*C_;
        bf16x8 qf[8];
        #pragma unroll
        for (int cc = 0; cc < 8; ++cc)
            qf[cc] = *(const bf16x8*)(Qb + (size_t)(i0 + 32*qt + l31)*C_ + 16*cc + 8*h);

        f32x16 acc[4];
        #pragma unroll
        for (int ct = 0; ct < 4; ++ct)
            #pragma unroll
            for (int r = 0; r < 16; ++r) acc[ct][r] = 0.f;
        float ps0 = 0.f, ps1 = 0.f, ps2 = 0.f, ps3 = 0.f;

        const u16* Kbase = Ksw + ((size_t)(b*128 + ks*32)*8)*512;   // stripe tile 0
        bf16x8 kf[8], kn[8];
        #pragma unroll
        for (int cc = 0; cc < 8; ++cc)
            kf[cc] = *(const bf16x8*)(Kbase + cc*512 + lane*8);
        bf16x8 v1[4], v2[4], w1[4], w2[4];
        #pragma unroll
        for (int ct = 0; ct < 4; ++ct) {
            const u16* vb = Vsw + (((size_t)(b*4 + ct)*128 + ks*32)*2)*512;
            v1[ct] = *(const bf16x8*)(vb + lane*8);
            v2[ct] = *(const bf16x8*)(vb + 512 + lane*8);
        }

        for (int it = 0; it < 32; ++it) {
            f32x16 s;
            #pragma unroll
            for (int r = 0; r < 16; ++r) s[r] = 0.f;
            #pragma unroll
            for (int cc = 0; cc < 8; ++cc)
                s = __builtin_amdgcn_mfma_f32_32x32x16_bf16(kf[cc], qf[cc], s, 0, 0, 0);
            int itn = (it + 1) & 31;
            {
                const u16* Kn = Kbase + ((size_t)itn*8)*512;
                #pragma unroll
                for (int cc = 0; cc < 8; ++cc)
                    kn[cc] = *(const bf16x8*)(Kn + cc*512 + lane*8);
            }
            {
                int Tn = ks*32 + itn;
                #pragma unroll
                for (int ct = 0; ct < 4; ++ct) {
                    const u16* vb = Vsw + (((size_t)(b*4 + ct)*128 + Tn)*2)*512;
                    w1[ct] = *(const bf16x8*)(vb + lane*8);
                    w2[ct] = *(const bf16x8*)(vb + 512 + lane*8);
                }
            }
            float p[16];
            #pragma unroll
            for (int r = 0; r < 16; ++r)
                p[r] = __builtin_amdgcn_exp2f(s[r] - mq);
            #pragma unroll
            for (int r = 0; r < 16; r += 4) {
                ps0 += p[r];     ps1 += p[r + 1];
                ps2 += p[r + 2]; ps3 += p[r + 3];
            }
            union { bf16x8 v; unsigned u[4]; } pf1, pf2;
            pf1.u[0] = cvtpk(p[0],  p[1]);  pf1.u[1] = cvtpk(p[2],  p[3]);
            pf1.u[2] = cvtpk(p[4],  p[5]);  pf1.u[3] = cvtpk(p[6],  p[7]);
            pf2.u[0] = cvtpk(p[8],  p[9]);  pf2.u[1] = cvtpk(p[10], p[11]);
            pf2.u[2] = cvtpk(p[12], p[13]); pf2.u[3] = cvtpk(p[14], p[15]);
            #pragma unroll
            for (int ct = 0; ct < 4; ++ct) {
                acc[ct] = __builtin_amdgcn_mfma_f32_32x32x16_bf16(v1[ct], pf1.v, acc[ct], 0, 0, 0);
                acc[ct] = __builtin_amdgcn_mfma_f32_32x32x16_bf16(v2[ct], pf2.v, acc[ct], 0, 0, 0);
            }
            #pragma unroll
            for (int cc = 0; cc < 8; ++cc) kf[cc] = kn[cc];
            #pragma unroll
            for (int ct = 0; ct < 4; ++ct) { v1[ct] = w1[ct]; v2[ct] = w2[ct]; }
        }

        float psum = (ps0 + ps1) + (ps2 + ps3);
        psum += __shfl_xor(psum, 32);
        if (lane < 32) sm.c.lW[w][l31] = psum;
        for (int i = 0; i < 4; ++i) {
            if (ks == i) {
                int q = 32*qt + l31;
                #pragma unroll
                for (int ct = 0; ct < 4; ++ct)
                    #pragma unroll
                    for (int qd = 0; qd < 4; ++qd) {
                        int c = 32*ct + 8*qd + 4*h;
                        float4 vv;
                        vv.x = acc[ct][4*qd + 0];
                        vv.y = acc[ct][4*qd + 1];
                        vv.z = acc[ct][4*qd + 2];
                        vv.w = acc[ct][4*qd + 3];
                        if (i == 0) {
                            *(float4*)(sm.c.Ob + q*132 + c) = vv;
                        } else {
                            float4 o = *(const float4*)(sm.c.Ob + q*132 + c);
                            o.x += vv.x; o.y += vv.y; o.z += vv.z; o.w += vv.w;
                            *(float4*)(sm.c.Ob + q*132 + c) = o;
                        }
                    }
            }
            __syncthreads();
        }
        int lo = lane & 15, hi = lane >> 4;
        int qtile = w >> 1, os = w & 1;
        int q = 16*qtile + lo;
        int qg = 4*(q >> 5), qc = q & 31;
        float linv = 1.f / (sm.c.lW[qg][qc] + sm.c.lW[qg+1][qc] + sm.c.lW[qg+2][qc] + sm.c.lW[qg+3][qc]);
        bf16x8 aa[4];
        #pragma unroll
        for (int ch = 0; ch < 4; ++ch) {
            float4 ua = *(const float4*)(sm.c.Ob + q*132 + 32*ch + 8*hi);
            float4 ub = *(const float4*)(sm.c.Ob + q*132 + 32*ch + 8*hi + 4);
            union { bf16x8 hh; unsigned u[4]; } pkd;
            pkd.u[0] = cvtpk(ua.x*linv, ua.y*linv);
            pkd.u[1] = cvtpk(ua.z*linv, ua.w*linv);
            pkd.u[2] = cvtpk(ub.x*linv, ub.y*linv);
            pkd.u[3] = cvtpk(ub.z*linv, ub.w*linv);
            aa[ch] = pkd.hh;
        }
        #pragma unroll
        for (int ot = 0; ot < 4; ++ot) {
            int ob = 64*os + 16*ot;
            f32x4 pr = (f32x4){0.f, 0.f, 0.f, 0.f};
            #pragma unroll
            for (int ch = 0; ch < 4; ++ch) {
                bf16x8 bw = *(const bf16x8*)(pwbf + (size_t)(ob + lo)*C_ + 32*ch + 8*hi);
                pr = __builtin_amdgcn_mfma_f32_16x16x32_bf16(aa[ch], bw, pr, 0, 0, 0);
            }
            int o = ob + lo;
            float pbv = pb[o];
            size_t base = ((size_t)(b*C_ + o))*N_ + i0 + 16*qtile + 4*hi;
            float4 xr = *(const float4*)(x + base);
            float4 res;
            res.x = xr.x + pr[0] + pbv;
            res.y = xr.y + pr[1] + pbv;
            res.z = xr.z + pr[2] + pbv;
            res.w = xr.w + pr[3] + pbv;
            *(float4*)(out + base) = res;
        }
    }
}

// =======================================================================
// Fallback path (3 separate kernels, identical to R1) in case cooperative
// launch is rejected by the runtime/graph capture.
// =======================================================================
__global__ __launch_bounds__(256) void prep_kernel(const float* __restrict__ x,
                                                   const float* __restrict__ qw,
                                                   const float* __restrict__ pw,
                                                   float* __restrict__ stats2,
                                                   u16* __restrict__ qwbf,
                                                   u16* __restrict__ pwbf) {
    int blk = blockIdx.x;
    if (blk < 256) {
        __shared__ float rs[4], rss[4];
        int bg = blk >> 3, chunk = blk & 7;
        const float4* xp = (const float4*)(x + (size_t)bg * (CperG * N_)) + chunk * 2048;
        float s = 0.f, ss = 0.f;
        for (int i = threadIdx.x; i < 2048; i += 256) {
            float4 v = xp[i];
            s  += v.x + v.y + v.z + v.w;
            ss += v.x*v.x + v.y*v.y + v.z*v.z + v.w*v.w;
        }
        #pragma unroll
        for (int off = 32; off > 0; off >>= 1) {
            s  += __shfl_down(s, off);
            ss += __shfl_down(ss, off);
        }
        int wv = threadIdx.x >> 6, ln = threadIdx.x & 63;
        if (ln == 0) { rs[wv] = s; rss[wv] = ss; }
        __syncthreads();
        if (threadIdx.x == 0) {
            stats2[blk*2]     = rs[0] + rs[1] + rs[2] + rs[3];
            stats2[blk*2 + 1] = rss[0] + rss[1] + rss[2] + rss[3];
        }
    } else {
        int fidx = ((blk - 256) * 256 + threadIdx.x) * 4;
        float4 v;
        u16* dst;
        if (fidx < 3*C_*C_) { v = *(const float4*)(qw + fidx); dst = qwbf + fidx; }
        else { int j = fidx - 3*C_*C_; v = *(const float4*)(pw + j); dst = pwbf + j; }
        ushort4 o;
        o.x = f2bf(v.x); o.y = f2bf(v.y); o.z = f2bf(v.z); o.w = f2bf(v.w);
        *(ushort4*)dst = o;
    }
}

__global__ __launch_bounds__(256, 3) void qkv_kernel(const float* __restrict__ x,
                                                     const float* __restrict__ stats2,
                                                     const float* __restrict__ nw,
                                                     const float* __restrict__ nb,
                                                     const u16* __restrict__ qwbf,
                                                     const float* __restrict__ qb,
                                                     u16* __restrict__ Qt,
                                                     u16* __restrict__ Ksw,
                                                     u16* __restrict__ Vsw,
                                                     float* __restrict__ qn2,
                                                     int* __restrict__ kmaxI) {
    int blk = blockIdx.x & 255;
    int sec = blockIdx.x >> 8;          // 0=Q, 1=K, 2=V
    int n0 = (blk & 63) * 64;
    int b  = blk >> 6;
    __shared__ u16 hs[64 * HS];
    __shared__ u16 Wl[64 * HS];
    __shared__ float gmean[8], grstd[8];
    int t = threadIdx.x;
    const float invM = 1.f / (float)(CperG * N_);
    if (t < 8) {
        const float* sp = stats2 + (size_t)(b*G_ + t)*16;
        float S = 0.f, SS = 0.f;
        #pragma unroll
        for (int k2 = 0; k2 < 8; ++k2) { S += sp[k2*2]; SS += sp[k2*2 + 1]; }
        float mean = S * invM;
        gmean[t] = mean;
        grstd[t] = rsqrtf(SS * invM - mean*mean + EPS_);
    }
    __syncthreads();
    #pragma unroll
    for (int r = 0; r < 8; ++r) {
        int idx = t + (r << 8);
        int c = idx >> 4, n4 = idx & 15;
        int g = c >> 4;
        float wgt = nw[c] * grstd[g];
        float bia = nb[c] - gmean[g] * wgt;
        float4 xv = *(const float4*)(x + ((size_t)(b*C_ + c))*N_ + n0 + n4*4);
        int base = (n4*4) * HS + c;
        unsigned u01 = cvtpk(xv.x*wgt + bia, xv.y*wgt + bia);
        unsigned u23 = cvtpk(xv.z*wgt + bia, xv.w*wgt + bia);
        hs[base         ] = (u16)(u01 & 0xffffu);
        hs[base +     HS] = (u16)(u01 >> 16);
        hs[base + 2 * HS] = (u16)(u23 & 0xffffu);
        hs[base + 3 * HS] = (u16)(u23 >> 16);
    }
    __syncthreads();
    int w = t >> 6, lane = t & 63, lo = lane & 15, hi = lane >> 4;
    bf16x8 hf[4];
    #pragma unroll
    for (int ch = 0; ch < 4; ++ch)
        hf[ch] = *(const bf16x8*)(hs + (16*w + lo)*HS + 32*ch + 8*hi);

    int Tb = (n0 >> 5) + (w >> 1);
    float nq = 0.f, nk = 0.f;
    for (int ckj = 0; ckj < 2; ++ckj) {
        int ck = 2*sec + ckj;
        {
            int r = t >> 2, p = t & 3;
            const u16* src = qwbf + (size_t)(ck*64 + r)*C_ + p*32;
            u16* dst = Wl + r*HS + p*32;
            #pragma unroll
            for (int k2 = 0; k2 < 4; ++k2)
                *(uint4*)(dst + 8*k2) = *(const uint4*)(src + 8*k2);
        }
        __syncthreads();
        #pragma unroll
        for (int ot = 0; ot < 4; ++ot) {
            int o16 = ck*64 + ot*16;
            bf16x8 wf[4];
            #pragma unroll
            for (int ch = 0; ch < 4; ++ch)
                wf[ch] = *(const bf16x8*)(Wl + (ot*16 + lo)*HS + 32*ch + 8*hi);
            if (o16 < 2*C_) {
                f32x4 acc = (f32x4){0.f, 0.f, 0.f, 0.f};
                #pragma unroll
                for (int ch = 0; ch < 4; ++ch)
                    acc = __builtin_amdgcn_mfma_f32_16x16x32_bf16(wf[ch], hf[ch], acc, 0, 0, 0);
                float4 bv = *(const float4*)(qb + o16 + 4*hi);
                int n = n0 + 16*w + lo;
                if (o16 < C_) {
                    float q0 = (acc[0] + bv.x) * SCALE2_;
                    float q1 = (acc[1] + bv.y) * SCALE2_;
                    float q2 = (acc[2] + bv.z) * SCALE2_;
                    float q3 = (acc[3] + bv.w) * SCALE2_;
                    nq += (q0*q0 + q1*q1) + (q2*q2 + q3*q3);
                    union { ushort4 s4; unsigned u[2]; } o4;
                    o4.u[0] = cvtpk(q0, q1);
                    o4.u[1] = cvtpk(q2, q3);
                    *(ushort4*)(Qt + ((size_t)b*N_ + n)*C_ + o16 + 4*hi) = o4.s4;
                } else {
                    float k0 = acc[0] + bv.x, k1 = acc[1] + bv.y;
                    float k2 = acc[2] + bv.z, k3 = acc[3] + bv.w;
                    nk += (k0*k0 + k1*k1) + (k2*k2 + k3*k3);
                    union { ushort4 s4; unsigned u[2]; } o4;
                    o4.u[0] = cvtpk(k0, k1);
                    o4.u[1] = cvtpk(k2, k3);
                    int cc = (o16 - C_) >> 4;
                    int lp = (16*(w & 1) + lo) + 32*(hi >> 1);
                    size_t fb = ((size_t)(b*128 + Tb)*8 + cc)*512;
                    *(ushort4*)(Ksw + fb + lp*8 + 4*(hi & 1)) = o4.s4;
                }
            } else {
                f32x4 acc = (f32x4){0.f, 0.f, 0.f, 0.f};
                #pragma unroll
                for (int ch = 0; ch < 4; ++ch)
                    acc = __builtin_amdgcn_mfma_f32_16x16x32_bf16(hf[ch], wf[ch], acc, 0, 0, 0);
                float bia = qb[o16 + lo];
                union { ushort4 s4; unsigned u[2]; } o4;
                o4.u[0] = cvtpk(acc[0] + bia, acc[1] + bia);
                o4.u[1] = cvtpk(acc[2] + bia, acc[3] + bia);
                int m  = (o16 - 2*C_) >> 4;
                int ct = m >> 1;
                int lp = (16*(m & 1) + lo) + 32*(hi & 1);
                size_t fb = (((size_t)(b*4 + ct)*128 + Tb)*2 + (w & 1))*512;
                *(ushort4*)(Vsw + fb + lp*8 + 4*(hi >> 1)) = o4.s4;
            }
        }
        __syncthreads();
    }
    if (sec == 0) {
        nq += __shfl_xor(nq, 16); nq += __shfl_xor(nq, 32);
        if (lane < 16) qn2[(size_t)b*N_ + n0 + 16*w + lo] = nq;
    } else if (sec == 1) {
        nk += __shfl_xor(nk, 16); nk += __shfl_xor(nk, 32);
        #pragma unroll
        for (int off = 1; off < 16; off <<= 1)
            nk = fmaxf(nk, __shfl_xor(nk, off));
        if (lane == 0) atomicMax(&kmaxI[b], __float_as_int(nk));
    }
}

__global__ __launch_bounds__(512, 2) void attn_kernel(const u16* __restrict__ Qt,
                                                      const u16* __restrict__ Ksw,
                                                      const u16* __restrict__ Vsw,
                                                      const float* __restrict__ qn2,
                                                      const int* __restrict__ kmaxI,
                                                      const u16* __restrict__ pwbf,
                                                      const float* __restrict__ pb,
                                                      const float* __restrict__ x,
                                                      float* __restrict__ out) {
    int lb = blockIdx.x;
    int b  = lb & 3;
    int i0 = 64 * (lb >> 2);
    int t = threadIdx.x;
    int w = t >> 6, lane = t & 63;
    int l31 = lane & 31, h = lane >> 5;
    int qt = w >> 2, ks = w & 3;

    __shared__ float Ob[64 * 132];
    __shared__ float lW[8][32];

    float kmax = sqrtf(__int_as_float(kmaxI[b]));
    float mq = sqrtf(qn2[(size_t)b*N_ + i0 + 32*qt + l31]) * kmax * 1.02f + 1e-6f;

    const u16* Qb = Qt + (size_t)b*N_*C_;
    bf16x8 qf[8];
    #pragma unroll
    for (int cc = 0; cc < 8; ++cc)
        qf[cc] = *(const bf16x8*)(Qb + (size_t)(i0 + 32*qt + l31)*C_ + 16*cc + 8*h);

    f32x16 acc[4];
    #pragma unroll
    for (int ct = 0; ct < 4; ++ct)
        #pragma unroll
        for (int r = 0; r < 16; ++r) acc[ct][r] = 0.f;
    float ps0 = 0.f, ps1 = 0.f, ps2 = 0.f, ps3 = 0.f;

    const u16* Kbase = Ksw + ((size_t)(b*128 + ks*32)*8)*512;
    bf16x8 kf[8], kn[8];
    #pragma unroll
    for (int cc = 0; cc < 8; ++cc)
        kf[cc] = *(const bf16x8*)(Kbase + cc*512 + lane*8);
    bf16x8 v1[4], v2[4], w1[4], w2[4];
    #pragma unroll
    for (int ct = 0; ct < 4; ++ct) {
        const u16* vb = Vsw + (((size_t)(b*4 + ct)*128 + ks*32)*2)*512;
        v1[ct] = *(const bf16x8*)(vb + lane*8);
        v2[ct] = *(const bf16x8*)(vb + 512 + lane*8);
    }

    for (int it = 0; it < 32; ++it) {
        f32x16 s;
        #pragma unroll
        for (int r = 0; r < 16; ++r) s[r] = 0.f;
        #pragma unroll
        for (int cc = 0; cc < 8; ++cc)
            s = __builtin_amdgcn_mfma_f32_32x32x16_bf16(kf[cc], qf[cc], s, 0, 0, 0);
        int itn = (it + 1) & 31;
        {
            const u16* Kn = Kbase + ((size_t)itn*8)*512;
            #pragma unroll
            for (int cc = 0; cc < 8; ++cc)
                kn[cc] = *(const bf16x8*)(Kn + cc*512 + lane*8);
        }
        {
            int Tn = ks*32 + itn;
            #pragma unroll
            for (int ct = 0; ct < 4; ++ct) {
                const u16* vb = Vsw + (((size_t)(b*4 + ct)*128 + Tn)*2)*512;
                w1[ct] = *(const bf16x8*)(vb + lane*8);
                w2[ct] = *(const bf16x8*)(vb + 512 + lane*8);
            }
        }
        float p[16];
        #pragma unroll
        for (int r = 0; r < 16; ++r)
            p[r] = __builtin_amdgcn_exp2f(s[r] - mq);
        #pragma unroll
        for (int r = 0; r < 16; r += 4) {
            ps0 += p[r];     ps1 += p[r + 1];
            ps2 += p[r + 2]; ps3 += p[r + 3];
        }
        union { bf16x8 v; unsigned u[4]; } pf1, pf2;
        pf1.u[0] = cvtpk(p[0],  p[1]);  pf1.u[1] = cvtpk(p[2],  p[3]);
        pf1.u[2] = cvtpk(p[4],  p[5]);  pf1.u[3] = cvtpk(p[6],  p[7]);
        pf2.u[0] = cvtpk(p[8],  p[9]);  pf2.u[1] = cvtpk(p[10], p[11]);
        pf2.u[2] = cvtpk(p[12], p[13]); pf2.u[3] = cvtpk(p[14], p[15]);
        #pragma unroll
        for (int ct = 0; ct < 4; ++ct) {
            acc[ct] = __builtin_amdgcn_mfma_f32_32x32x16_bf16(v1[ct], pf1.v, acc[ct], 0, 0, 0);
            acc[ct] = __builtin_amdgcn_mfma_f32_32x32x16_bf16(v2[ct], pf2.v, acc[ct], 0, 0, 0);
        }
        #pragma unroll
        for (int cc = 0; cc < 8; ++cc) kf[cc] = kn[cc];
        #pragma unroll
        for (int ct = 0; ct < 4; ++ct) { v1[ct] = w1[ct]; v2[ct] = w2[ct]; }
    }

    float psum = (ps0 + ps1) + (ps2 + ps3);
    psum += __shfl_xor(psum, 32);
    if (lane < 32) lW[w][l31] = psum;
    for (int i = 0; i < 4; ++i) {
        if (ks == i) {
            int q = 32*qt + l31;
            #pragma unroll
            for (int ct = 0; ct < 4; ++ct)
                #pragma unroll
                for (int qd = 0; qd < 4; ++qd) {
                    int c = 32*ct + 8*qd + 4*h;
                    float4 vv;
                    vv.x = acc[ct][4*qd + 0];
                    vv.y = acc[ct][4*qd + 1];
                    vv.z = acc[ct][4*qd + 2];
                    vv.w = acc[ct][4*qd + 3];
                    if (i == 0) {
                        *(float4*)(Ob + q*132 + c) = vv;
                    } else {
                        float4 o = *(const float4*)(Ob + q*132 + c);
                        o.x += vv.x; o.y += vv.y; o.z += vv.z; o.w += vv.w;
                        *(float4*)(Ob + q*132 + c) = o;
                    }
                }
        }
        __syncthreads();
    }
    int lo = lane & 15, hi = lane >> 4;
    int qtile = w >> 1, os = w & 1;
    int q = 16*qtile + lo;
    int qg = 4*(q >> 5), qc = q & 31;
    float linv = 1.f / (lW[qg][qc] + lW[qg+1][qc] + lW[qg+2][qc] + lW[qg+3][qc]);
    bf16x8 aa[4];
    #pragma unroll
    for (int ch = 0; ch < 4; ++ch) {
        float4 ua = *(const float4*)(Ob + q*132 + 32*ch + 8*hi);
        float4 ub = *(const float4*)(Ob + q*132 + 32*ch + 8*hi + 4);
        union { bf16x8 hh; unsigned u[4]; } pkd;
        pkd.u[0] = cvtpk(ua.x*linv, ua.y*linv);
        pkd.u[1] = cvtpk(ua.z*linv, ua.w*linv);
        pkd.u[2] = cvtpk(ub.x*linv, ub.y*linv);
        pkd.u[3] = cvtpk(ub.z*linv, ub.w*linv);
        aa[ch] = pkd.hh;
    }
    #pragma unroll
    for (int ot = 0; ot < 4; ++ot) {
        int ob = 64*os + 16*ot;
        f32x4 pr = (f32x4){0.f, 0.f, 0.f, 0.f};
        #pragma unroll
        for (int ch = 0; ch < 4; ++ch) {
            bf16x8 bw = *(const bf16x8*)(pwbf + (size_t)(ob + lo)*C_ + 32*ch + 8*hi);
            pr = __builtin_amdgcn_mfma_f32_16x16x32_bf16(aa[ch], bw, pr, 0, 0, 0);
        }
        int o = ob + lo;
        float pbv = pb[o];
        size_t base = ((size_t)(b*C_ + o))*N_ + i0 + 16*qtile + 4*hi;
        float4 xr = *(const float4*)(x + base);
        float4 res;
        res.x = xr.x + pr[0] + pbv;
        res.y = xr.y + pr[1] + pbv;
        res.z = xr.z + pr[2] + pbv;
        res.w = xr.w + pr[3] + pbv;
        *(float4*)(out + base) = res;
    }
}

extern "C" void kernel_launch(void* const* d_in, const int* in_sizes, int n_in,
                              void* d_out, int out_size, void* d_ws, size_t ws_size,
                              hipStream_t stream) {
    const float* x  = (const float*)d_in[0];
    const float* nw = (const float*)d_in[1];
    const float* nb = (const float*)d_in[2];
    const float* qw = (const float*)d_in[3];
    const float* qb = (const float*)d_in[4];
    const float* pw = (const float*)d_in[5];
    const float* pb = (const float*)d_in[6];
    float* out = (float*)d_out;

    // ws: [stats2 2KB][qn2 64KB][kmaxI 256B][qwbf 96KB][pwbf 32KB][Qt 4MB][Ksw 4MB][Vsw 4MB]
    char* p = (char*)d_ws;
    float* stats2 = (float*)p;                 p += 2048;
    float* qn2    = (float*)p;                 p += (size_t)B_*N_*4;
    int*   kmaxI  = (int*)p;                   p += 256;
    u16*   qwbf   = (u16*)p;                   p += (size_t)3*C_*C_*2;
    u16*   pwbf   = (u16*)p;                   p += (size_t)C_*C_*2;
    u16*   Qt     = (u16*)p;                   p += (size_t)B_*N_*C_*2;
    u16*   Ksw    = (u16*)p;                   p += (size_t)B_*N_*C_*2;
    u16*   Vsw    = (u16*)p;

    void* args[] = { (void*)&x, (void*)&nw, (void*)&nb, (void*)&qw, (void*)&qb,
                     (void*)&pw, (void*)&pb, (void*)&out,
                     (void*)&stats2, (void*)&qn2, (void*)&kmaxI,
                     (void*)&qwbf, (void*)&pwbf, (void*)&Qt, (void*)&Ksw, (void*)&Vsw };
    hipError_t err = hipLaunchCooperativeKernel((void*)fused_kernel, dim3(256), dim3(512),
                                                args, 0, stream);
    if (err != hipSuccess) {
        // fallback: 3-kernel path (R1)
        prep_kernel<<<dim3(320), 256, 0, stream>>>(x, qw, pw, stats2, qwbf, pwbf);
        qkv_kernel<<<dim3(768), 256, 0, stream>>>(x, stats2, nw, nb, qwbf, qb,
                                                  Qt, Ksw, Vsw, qn2, kmaxI);
        attn_kernel<<<dim3(256), 512, 0, stream>>>(Qt, Ksw, Vsw, qn2, kmaxI,
                                                   pwbf, pb, x, out);
    }
}

// Round 3
// 146.973 us; speedup vs baseline: 2.4793x; 2.4793x over previous
//
#include <hip/hip_runtime.h>

typedef float  f32x4   __attribute__((ext_vector_type(4)));
typedef float  f32x16  __attribute__((ext_vector_type(16)));
typedef short  bf16x8  __attribute__((ext_vector_type(8)));
typedef unsigned short u16;
typedef unsigned int   u32;

constexpr int B_ = 4;
constexpr int C_ = 128;
constexpr int N_ = 4096;
constexpr int G_ = 8;
constexpr int CperG = 16;
constexpr float EPS_ = 1e-5f;
// 1/sqrt(C) * log2(e): Q pre-scaled so the softmax exp is a bare v_exp_f32 (exp2)
constexpr float SCALE2_ = 0.08838834764831845f * 1.4426950408889634f;

__device__ inline u16 f2bf(float f) {
    union { float f; unsigned u; } v; v.f = f;
    unsigned r = v.u + 0x7fffu + ((v.u >> 16) & 1u);  // RNE
    return (u16)(r >> 16);
}
// hardware packed f32->bf16 (RNE), 1 instr instead of ~10
__device__ inline unsigned cvtpk(float lo, float hi) {
    unsigned r;
    asm("v_cvt_pk_bf16_f32 %0, %1, %2" : "=v"(r) : "v"(lo), "v"(hi));
    return r;
}
// async global->LDS, 16B per lane. LDS dst is wave-uniform base (+lane*16 by HW);
// global src is per-lane. Our frag layout (lane*8 u16 within 1KB frag) matches exactly.
__device__ inline void glds16(const u16* g, u16* l) {
    __builtin_amdgcn_global_load_lds(
        (const __attribute__((address_space(1))) u32*)g,
        (__attribute__((address_space(3))) u32*)l,
        16, 0, 0);
}

// ---------------- 1. prep: GN partials + weight bf16 conversion ----------------
__global__ __launch_bounds__(256) void prep_kernel(const float* __restrict__ x,
                                                   const float* __restrict__ qw,
                                                   const float* __restrict__ pw,
                                                   float* __restrict__ stats2,
                                                   u16* __restrict__ qwbf,
                                                   u16* __restrict__ pwbf) {
    int blk = blockIdx.x;
    if (blk < 256) {
        __shared__ float rs[4], rss[4];
        int bg = blk >> 3, chunk = blk & 7;
        const float4* xp = (const float4*)(x + (size_t)bg * (CperG * N_)) + chunk * 2048;
        float s = 0.f, ss = 0.f;
        for (int i = threadIdx.x; i < 2048; i += 256) {
            float4 v = xp[i];
            s  += v.x + v.y + v.z + v.w;
            ss += v.x*v.x + v.y*v.y + v.z*v.z + v.w*v.w;
        }
        #pragma unroll
        for (int off = 32; off > 0; off >>= 1) {
            s  += __shfl_down(s, off);
            ss += __shfl_down(ss, off);
        }
        int wv = threadIdx.x >> 6, ln = threadIdx.x & 63;
        if (ln == 0) { rs[wv] = s; rss[wv] = ss; }
        __syncthreads();
        if (threadIdx.x == 0) {
            stats2[blk*2]     = rs[0] + rs[1] + rs[2] + rs[3];
            stats2[blk*2 + 1] = rss[0] + rss[1] + rss[2] + rss[3];
        }
    } else {
        int fidx = ((blk - 256) * 256 + threadIdx.x) * 4;
        float4 v;
        u16* dst;
        if (fidx < 3*C_*C_) { v = *(const float4*)(qw + fidx); dst = qwbf + fidx; }
        else { int j = fidx - 3*C_*C_; v = *(const float4*)(pw + j); dst = pwbf + j; }
        ushort4 o;
        o.x = f2bf(v.x); o.y = f2bf(v.y); o.z = f2bf(v.z); o.w = f2bf(v.w);
        *(ushort4*)dst = o;
    }
}

// ---------------- 2. QKV via MFMA -> Q row-major; K,V in MFMA-FRAGMENT order -------
// (identical to R1: 3-way section split, grid 768, sec 0=Q / 1=K / 2=V)
constexpr int HS = 136;   // padded row stride (u16)

__global__ __launch_bounds__(256, 3) void qkv_kernel(const float* __restrict__ x,
                                                     const float* __restrict__ stats2,
                                                     const float* __restrict__ nw,
                                                     const float* __restrict__ nb,
                                                     const u16* __restrict__ qwbf,
                                                     const float* __restrict__ qb,
                                                     u16* __restrict__ Qt,
                                                     u16* __restrict__ Ksw,
                                                     u16* __restrict__ Vsw,
                                                     float* __restrict__ qn2,
                                                     int* __restrict__ kmaxI) {
    int blk = blockIdx.x & 255;
    int sec = blockIdx.x >> 8;          // 0=Q, 1=K, 2=V
    int n0 = (blk & 63) * 64;
    int b  = blk >> 6;
    __shared__ u16 hs[64 * HS];
    __shared__ u16 Wl[64 * HS];
    __shared__ float gmean[8], grstd[8];
    int t = threadIdx.x;
    const float invM = 1.f / (float)(CperG * N_);
    if (t < 8) {
        const float* sp = stats2 + (size_t)(b*G_ + t)*16;
        float S = 0.f, SS = 0.f;
        #pragma unroll
        for (int k2 = 0; k2 < 8; ++k2) { S += sp[k2*2]; SS += sp[k2*2 + 1]; }
        float mean = S * invM;
        gmean[t] = mean;
        grstd[t] = rsqrtf(SS * invM - mean*mean + EPS_);
    }
    __syncthreads();
    #pragma unroll
    for (int r = 0; r < 8; ++r) {
        int idx = t + (r << 8);
        int c = idx >> 4, n4 = idx & 15;
        int g = c >> 4;
        float wgt = nw[c] * grstd[g];
        float bia = nb[c] - gmean[g] * wgt;
        float4 xv = *(const float4*)(x + ((size_t)(b*C_ + c))*N_ + n0 + n4*4);
        int base = (n4*4) * HS + c;
        unsigned u01 = cvtpk(xv.x*wgt + bia, xv.y*wgt + bia);
        unsigned u23 = cvtpk(xv.z*wgt + bia, xv.w*wgt + bia);
        hs[base         ] = (u16)(u01 & 0xffffu);
        hs[base +     HS] = (u16)(u01 >> 16);
        hs[base + 2 * HS] = (u16)(u23 & 0xffffu);
        hs[base + 3 * HS] = (u16)(u23 >> 16);
    }
    __syncthreads();
    int w = t >> 6, lane = t & 63, lo = lane & 15, hi = lane >> 4;
    bf16x8 hf[4];
    #pragma unroll
    for (int ch = 0; ch < 4; ++ch)
        hf[ch] = *(const bf16x8*)(hs + (16*w + lo)*HS + 32*ch + 8*hi);

    int Tb = (n0 >> 5) + (w >> 1);
    float nq = 0.f, nk = 0.f;
    for (int ckj = 0; ckj < 2; ++ckj) {
        int ck = 2*sec + ckj;
        {
            int r = t >> 2, p = t & 3;
            const u16* src = qwbf + (size_t)(ck*64 + r)*C_ + p*32;
            u16* dst = Wl + r*HS + p*32;
            #pragma unroll
            for (int k2 = 0; k2 < 4; ++k2)
                *(uint4*)(dst + 8*k2) = *(const uint4*)(src + 8*k2);
        }
        __syncthreads();
        #pragma unroll
        for (int ot = 0; ot < 4; ++ot) {
            int o16 = ck*64 + ot*16;
            bf16x8 wf[4];
            #pragma unroll
            for (int ch = 0; ch < 4; ++ch)
                wf[ch] = *(const bf16x8*)(Wl + (ot*16 + lo)*HS + 32*ch + 8*hi);
            if (o16 < 2*C_) {
                // Q/K: A=W (m=o), B=h (n=px) -> lane holds D[o=o16+4hi+r][px=n0+16w+lo]
                f32x4 acc = (f32x4){0.f, 0.f, 0.f, 0.f};
                #pragma unroll
                for (int ch = 0; ch < 4; ++ch)
                    acc = __builtin_amdgcn_mfma_f32_16x16x32_bf16(wf[ch], hf[ch], acc, 0, 0, 0);
                float4 bv = *(const float4*)(qb + o16 + 4*hi);
                int n = n0 + 16*w + lo;
                if (o16 < C_) {
                    float q0 = (acc[0] + bv.x) * SCALE2_;
                    float q1 = (acc[1] + bv.y) * SCALE2_;
                    float q2 = (acc[2] + bv.z) * SCALE2_;
                    float q3 = (acc[3] + bv.w) * SCALE2_;
                    nq += (q0*q0 + q1*q1) + (q2*q2 + q3*q3);
                    union { ushort4 s4; unsigned u[2]; } o4;
                    o4.u[0] = cvtpk(q0, q1);
                    o4.u[1] = cvtpk(q2, q3);
                    *(ushort4*)(Qt + ((size_t)b*N_ + n)*C_ + o16 + 4*hi) = o4.s4;
                } else {
                    float k0 = acc[0] + bv.x, k1 = acc[1] + bv.y;
                    float k2 = acc[2] + bv.z, k3 = acc[3] + bv.w;
                    nk += (k0*k0 + k1*k1) + (k2*k2 + k3*k3);
                    union { ushort4 s4; unsigned u[2]; } o4;
                    o4.u[0] = cvtpk(k0, k1);
                    o4.u[1] = cvtpk(k2, k3);
                    int cc = (o16 - C_) >> 4;
                    int lp = (16*(w & 1) + lo) + 32*(hi >> 1);
                    size_t fb = ((size_t)(b*128 + Tb)*8 + cc)*512;
                    *(ushort4*)(Ksw + fb + lp*8 + 4*(hi & 1)) = o4.s4;
                }
            } else {
                // V: A=h (m=px), B=W (n=o) -> lane holds D[px=n0+16w+4hi+r][o=o16-256+lo]
                f32x4 acc = (f32x4){0.f, 0.f, 0.f, 0.f};
                #pragma unroll
                for (int ch = 0; ch < 4; ++ch)
                    acc = __builtin_amdgcn_mfma_f32_16x16x32_bf16(hf[ch], wf[ch], acc, 0, 0, 0);
                float bia = qb[o16 + lo];
                union { ushort4 s4; unsigned u[2]; } o4;
                o4.u[0] = cvtpk(acc[0] + bia, acc[1] + bia);
                o4.u[1] = cvtpk(acc[2] + bia, acc[3] + bia);
                int m  = (o16 - 2*C_) >> 4;
                int ct = m >> 1;
                int lp = (16*(m & 1) + lo) + 32*(hi & 1);
                size_t fb = (((size_t)(b*4 + ct)*128 + Tb)*2 + (w & 1))*512;
                *(ushort4*)(Vsw + fb + lp*8 + 4*(hi >> 1)) = o4.s4;
            }
        }
        __syncthreads();
    }
    if (sec == 0) {
        nq += __shfl_xor(nq, 16); nq += __shfl_xor(nq, 32);
        if (lane < 16) qn2[(size_t)b*N_ + n0 + 16*w + lo] = nq;
    } else if (sec == 1) {
        nk += __shfl_xor(nk, 16); nk += __shfl_xor(nk, 32);
        #pragma unroll
        for (int off = 1; off < 16; off <<= 1)
            nk = fmaxf(nk, __shfl_xor(nk, off));
        if (lane == 0) atomicMax(&kmaxI[b], __float_as_int(nk));  // poison negative: safe
    }
}

// ------------- 3. MFMA attention with LDS-staged K/V (double-buffered) -------------
// 256 blocks (1/CU), 512 thr, 8 waves = 2 qt x 4 ks.  Keys in 128-key tiles
// (32 iters): waves 0-3 stage K frags (T'=w, cc=j), waves 4-7 stage V frags
// (ct=w-4, T'=j>>1, kk=j&1) via global_load_lds (identity copy of frag layout).
// Each wave computes sub-tile T'=ks from LDS. Halves L2 traffic (4->2 MB/block),
// replaces L2-latency loads with conflict-free ds_read_b128. One barrier/tile.
__global__ __launch_bounds__(512, 1) void attn_kernel(const u16* __restrict__ Qt,
                                                      const u16* __restrict__ Ksw,
                                                      const u16* __restrict__ Vsw,
                                                      const float* __restrict__ qn2,
                                                      const int* __restrict__ kmaxI,
                                                      const u16* __restrict__ pwbf,
                                                      const float* __restrict__ pb,
                                                      const float* __restrict__ x,
                                                      float* __restrict__ out) {
    int lb = blockIdx.x;
    int b  = lb & 3;                       // XCD-swizzle: batch locality in L2
    int i0 = 64 * (lb >> 2);
    int t = threadIdx.x;
    int w = t >> 6, lane = t & 63;
    int l31 = lane & 31, h = lane >> 5;
    int qt = w >> 2, ks = w & 3;

    // 128 KB: two 64KB buffers (K 16K u16 + V 16K u16 each); epilogue aliases buf0.
    __shared__ union {
        u16 kv[2][32768];
        struct { float Ob[64*132]; float lW[8][32]; } c;
    } sm;

    float kmax = sqrtf(__int_as_float(kmaxI[b]));
    float mq = sqrtf(qn2[(size_t)b*N_ + i0 + 32*qt + l31]) * kmax * 1.02f + 1e-6f;

    // persistent Q B-frags (query = i0 + 32qt + l31, chans 16cc + 8h)
    const u16* Qb = Qt + (size_t)b*N_*C_;
    bf16x8 qf[8];
    #pragma unroll
    for (int cc = 0; cc < 8; ++cc)
        qf[cc] = *(const bf16x8*)(Qb + (size_t)(i0 + 32*qt + l31)*C_ + 16*cc + 8*h);

    f32x16 acc[4];
    #pragma unroll
    for (int ct = 0; ct < 4; ++ct)
        #pragma unroll
        for (int r = 0; r < 16; ++r) acc[ct][r] = 0.f;
    float ps0 = 0.f, ps1 = 0.f, ps2 = 0.f, ps3 = 0.f;

    // ---- per-wave staging assignment: 8 frags each, running global pointers ----
    const u16* gs[8];
    int loff[8];
    size_t gstep;
    if (w < 4) {                           // K frags: T' = w, cc = j
        gstep = 16384;                     // tile step: 4*8*512 u16
        #pragma unroll
        for (int j = 0; j < 8; ++j) {
            gs[j]   = Ksw + ((size_t)(b*128 + w)*8 + j)*512 + lane*8;
            loff[j] = (w*8 + j)*512;
        }
    } else {                               // V frags: ct = w-4, T' = j>>1, kk = j&1
        gstep = 4096;                      // tile step: 4*2*512 u16
        int ct = w - 4;
        #pragma unroll
        for (int j = 0; j < 8; ++j) {
            int Tp = j >> 1, kk = j & 1;
            gs[j]   = Vsw + (((size_t)(b*4 + ct)*128 + Tp)*2 + kk)*512 + lane*8;
            loff[j] = 16384 + ((ct*4 + Tp)*2 + kk)*512;
        }
    }

    // prologue: stage tile 0 into buf 0
    #pragma unroll
    for (int j = 0; j < 8; ++j) { glds16(gs[j], sm.kv[0] + loff[j]); gs[j] += gstep; }
    __syncthreads();                       // drains vmcnt: tile 0 resident

    for (int tt = 0; tt < 32; ++tt) {
        // issue next tile's staging first (latency hides under this tile's compute)
        if (tt < 31) {
            u16* dst = sm.kv[(tt + 1) & 1];
            #pragma unroll
            for (int j = 0; j < 8; ++j) { glds16(gs[j], dst + loff[j]); gs[j] += gstep; }
        }
        const u16* kb = sm.kv[tt & 1];
        // ---- QK: one 32x32 S^T tile (keys tt*128 + ks*32 .., queries 32qt..) ----
        bf16x8 kf[8];
        #pragma unroll
        for (int cc = 0; cc < 8; ++cc)
            kf[cc] = *(const bf16x8*)(kb + (ks*8 + cc)*512 + lane*8);
        f32x16 s;
        #pragma unroll
        for (int r = 0; r < 16; ++r) s[r] = 0.f;
        #pragma unroll
        for (int cc = 0; cc < 8; ++cc)
            s = __builtin_amdgcn_mfma_f32_32x32x16_bf16(kf[cc], qf[cc], s, 0, 0, 0);
        // ---- V fragments for this sub-tile ----
        bf16x8 v1[4], v2[4];
        #pragma unroll
        for (int ct = 0; ct < 4; ++ct) {
            const u16* vbp = kb + 16384 + ((ct*4 + ks)*2)*512 + lane*8;
            v1[ct] = *(const bf16x8*)(vbp);
            v2[ct] = *(const bf16x8*)(vbp + 512);
        }
        // ---- bound softmax: p = exp2(S - m_q), no reductions ----
        float p[16];
        #pragma unroll
        for (int r = 0; r < 16; ++r)
            p[r] = __builtin_amdgcn_exp2f(s[r] - mq);
        #pragma unroll
        for (int r = 0; r < 16; r += 4) {
            ps0 += p[r];     ps1 += p[r + 1];
            ps2 += p[r + 2]; ps3 += p[r + 3];
        }
        union { bf16x8 v; unsigned u[4]; } pf1, pf2;
        pf1.u[0] = cvtpk(p[0],  p[1]);  pf1.u[1] = cvtpk(p[2],  p[3]);
        pf1.u[2] = cvtpk(p[4],  p[5]);  pf1.u[3] = cvtpk(p[6],  p[7]);
        pf2.u[0] = cvtpk(p[8],  p[9]);  pf2.u[1] = cvtpk(p[10], p[11]);
        pf2.u[2] = cvtpk(p[12], p[13]); pf2.u[3] = cvtpk(p[14], p[15]);
        // ---- PV: A = V frags, B = P (regs) ----
        #pragma unroll
        for (int ct = 0; ct < 4; ++ct) {
            acc[ct] = __builtin_amdgcn_mfma_f32_32x32x16_bf16(v1[ct], pf1.v, acc[ct], 0, 0, 0);
            acc[ct] = __builtin_amdgcn_mfma_f32_32x32x16_bf16(v2[ct], pf2.v, acc[ct], 0, 0, 0);
        }
        __syncthreads();   // drains next-tile staging; releases buf for overwrite
    }

    // ---------------- combine ks stripes (plain adds: shared m_q) ----------------
    float psum = (ps0 + ps1) + (ps2 + ps3);
    psum += __shfl_xor(psum, 32);
    if (lane < 32) sm.c.lW[w][l31] = psum;
    for (int i = 0; i < 4; ++i) {
        if (ks == i) {
            int q = 32*qt + l31;
            #pragma unroll
            for (int ct = 0; ct < 4; ++ct)
                #pragma unroll
                for (int qd = 0; qd < 4; ++qd) {
                    int c = 32*ct + 8*qd + 4*h;
                    float4 vv;
                    vv.x = acc[ct][4*qd + 0];
                    vv.y = acc[ct][4*qd + 1];
                    vv.z = acc[ct][4*qd + 2];
                    vv.w = acc[ct][4*qd + 3];
                    if (i == 0) {
                        *(float4*)(sm.c.Ob + q*132 + c) = vv;
                    } else {
                        float4 o = *(const float4*)(sm.c.Ob + q*132 + c);
                        o.x += vv.x; o.y += vv.y; o.z += vv.z; o.w += vv.w;
                        *(float4*)(sm.c.Ob + q*132 + c) = o;
                    }
                }
        }
        __syncthreads();
    }
    // ---------------- proj + bias + residual (verified r9 epilogue) ----------------
    int lo = lane & 15, hi = lane >> 4;
    int qtile = w >> 1, os = w & 1;
    int q = 16*qtile + lo;
    int qg = 4*(q >> 5), qc = q & 31;
    float linv = 1.f / (sm.c.lW[qg][qc] + sm.c.lW[qg+1][qc] + sm.c.lW[qg+2][qc] + sm.c.lW[qg+3][qc]);
    bf16x8 aa[4];
    #pragma unroll
    for (int ch = 0; ch < 4; ++ch) {
        float4 ua = *(const float4*)(sm.c.Ob + q*132 + 32*ch + 8*hi);
        float4 ub = *(const float4*)(sm.c.Ob + q*132 + 32*ch + 8*hi + 4);
        union { bf16x8 hh; unsigned u[4]; } pkd;
        pkd.u[0] = cvtpk(ua.x*linv, ua.y*linv);
        pkd.u[1] = cvtpk(ua.z*linv, ua.w*linv);
        pkd.u[2] = cvtpk(ub.x*linv, ub.y*linv);
        pkd.u[3] = cvtpk(ub.z*linv, ub.w*linv);
        aa[ch] = pkd.hh;
    }
    #pragma unroll
    for (int ot = 0; ot < 4; ++ot) {
        int ob = 64*os + 16*ot;
        f32x4 pr = (f32x4){0.f, 0.f, 0.f, 0.f};
        #pragma unroll
        for (int ch = 0; ch < 4; ++ch) {
            bf16x8 bw = *(const bf16x8*)(pwbf + (size_t)(ob + lo)*C_ + 32*ch + 8*hi);
            pr = __builtin_amdgcn_mfma_f32_16x16x32_bf16(aa[ch], bw, pr, 0, 0, 0);
        }
        int o = ob + lo;
        float pbv = pb[o];
        size_t base = ((size_t)(b*C_ + o))*N_ + i0 + 16*qtile + 4*hi;
        float4 xr = *(const float4*)(x + base);
        float4 res;
        res.x = xr.x + pr[0] + pbv;
        res.y = xr.y + pr[1] + pbv;
        res.z = xr.z + pr[2] + pbv;
        res.w = xr.w + pr[3] + pbv;
        *(float4*)(out + base) = res;
    }
}

extern "C" void kernel_launch(void* const* d_in, const int* in_sizes, int n_in,
                              void* d_out, int out_size, void* d_ws, size_t ws_size,
                              hipStream_t stream) {
    const float* x  = (const float*)d_in[0];
    const float* nw = (const float*)d_in[1];
    const float* nb = (const float*)d_in[2];
    const float* qw = (const float*)d_in[3];
    const float* qb = (const float*)d_in[4];
    const float* pw = (const float*)d_in[5];
    const float* pb = (const float*)d_in[6];
    float* out = (float*)d_out;

    // ws: [stats2 2KB][qn2 64KB][kmaxI 256B][qwbf 96KB][pwbf 32KB][Qt 4MB][Ksw 4MB][Vsw 4MB]
    char* p = (char*)d_ws;
    float* stats2 = (float*)p;                 p += 2048;
    float* qn2    = (float*)p;                 p += (size_t)B_*N_*4;
    int*   kmaxI  = (int*)p;                   p += 256;
    u16*   qwbf   = (u16*)p;                   p += (size_t)3*C_*C_*2;
    u16*   pwbf   = (u16*)p;                   p += (size_t)C_*C_*2;
    u16*   Qt     = (u16*)p;                   p += (size_t)B_*N_*C_*2;
    u16*   Ksw    = (u16*)p;                   p += (size_t)B_*N_*C_*2;
    u16*   Vsw    = (u16*)p;

    prep_kernel<<<dim3(320), 256, 0, stream>>>(x, qw, pw, stats2, qwbf, pwbf);
    qkv_kernel<<<dim3(768), 256, 0, stream>>>(x, stats2, nw, nb, qwbf, qb,
                                              Qt, Ksw, Vsw, qn2, kmaxI);
    attn_kernel<<<dim3(256), 512, 0, stream>>>(Qt, Ksw, Vsw, qn2, kmaxI,
                                               pwbf, pb, x, out);
}